// Round 13
// baseline (2667.282 us; speedup 1.0000x reference)
//
#include <hip/hip_runtime.h>
#include <stdint.h>
#include <cstdio>

#define B   256
#define T   1024
#define FIN 64
#define H   128
#define G4  512   // 4*H

typedef float vf16 __attribute__((ext_vector_type(16)));

// Inline activations (no OCML calls — R8: calls forced spills around them).
#define LOG2E 1.442695041f
__device__ __forceinline__ float fast_tanh(float x) {
    return fmaf(2.f, __builtin_amdgcn_rcpf(1.f + __builtin_amdgcn_exp2f(-2.f * LOG2E * x)), -1.f);
}

// DPP quad_perm cross-lane (VALU pipe, no LDS): xor1 = [1,0,3,2] = 0xB1,
// xor2 = [2,3,0,1] = 0x4E. lane^3 = QXOR1(QXOR2(x)).
#define QXOR1(x) __int_as_float(__builtin_amdgcn_update_dpp(0, __float_as_int(x), 0xB1, 0xf, 0xf, true))
#define QXOR2(x) __int_as_float(__builtin_amdgcn_update_dpp(0, __float_as_int(x), 0x4E, 0xf, 0xf, true))

// ----------------------------------------------------------------------------
// prep: transpose W_ih -> WT[k][j], bias sums, zero recurrent states
// ----------------------------------------------------------------------------
__global__ void prep_kernel(const float* __restrict__ W_ih0,
                            const float* __restrict__ b_ih0, const float* __restrict__ b_hh0,
                            const float* __restrict__ W_ih1,
                            const float* __restrict__ b_ih1, const float* __restrict__ b_hh1,
                            float* __restrict__ WT0, float* __restrict__ WT1,
                            float* __restrict__ bsum0, float* __restrict__ bsum1,
                            float* __restrict__ states /* 4*B*H */)
{
    int idx = blockIdx.x * blockDim.x + threadIdx.x;
    int n   = gridDim.x * blockDim.x;
    for (int i = idx; i < H * G4; i += n) { int k = i / G4, j = i % G4; WT1[i] = W_ih1[j * H + k]; }
    for (int i = idx; i < FIN * G4; i += n) { int k = i / G4, j = i % G4; WT0[i] = W_ih0[j * FIN + k]; }
    for (int i = idx; i < G4; i += n) { bsum0[i] = b_ih0[i] + b_hh0[i]; bsum1[i] = b_ih1[i] + b_hh1[i]; }
    for (int i = idx; i < 4 * B * H; i += n) states[i] = 0.f;
}

// ----------------------------------------------------------------------------
// gx GEMM, R21: R18/R20 structure (ROWS=16, single vf16 acc, constexpr
// stride) + EXPLICIT weight double-buffering (A/B vf16 pairs): chunk k+1's
// 32 weight loads issue BEFORE chunk k's 512 fmacs, so ~1000 cyc of fmac
// issue hides the ~200 cyc L2 weight-load latency.
//
// R20 post-mortem: waves_per_eu(5) neutral -> TLP isn't the lever; the
// gemm's 43% VALUBusy (R16 profile: no over-fetch, 8% HBM) is latency-
// stall, so add ILP instead. Live regs: 16 acc + 64 wt + ~35 ~ 115 < 128
// cap at waves_per_eu(4) (reverted from neutral 5).
// Per-output fmac order unchanged (chunks 0,32,64,96; same in-chunk
// sequence) -> bitwise-identical gx (absmax 0.0).
// ----------------------------------------------------------------------------
#define GW2(P0,P1,n)    ((n) < 16 ? P0[(n) & 15] : P1[(n) & 15])
#define GWS2(P0,P1,n,v) do { if ((n) < 16) P0[(n) & 15] = (v); else P1[(n) & 15] = (v); } while (0)

#define GLD4P(P0,P1,n) GWS2(P0,P1,(n), wp0[(long)(n) * G4]); GWS2(P0,P1,(n)+1, wp0[(long)((n)+1) * G4]); \
                       GWS2(P0,P1,(n)+2, wp0[(long)((n)+2) * G4]); GWS2(P0,P1,(n)+3, wp0[(long)((n)+3) * G4]);

#define GLOADP(P0,P1,kb) { \
    const float* __restrict__ wp0 = WT + (long)(kb) * G4 + j; \
    GLD4P(P0,P1,0) GLD4P(P0,P1,4) GLD4P(P0,P1,8) GLD4P(P0,P1,12) \
    GLD4P(P0,P1,16) GLD4P(P0,P1,20) GLD4P(P0,P1,24) GLD4P(P0,P1,28) }

#define GMAC4P(P0,P1,kk,r0) { \
    float4 v0 = *(const float4*)(x0 + (kk)); \
    float4 v1 = *(const float4*)(x1 + (kk)); \
    float4 v2 = *(const float4*)(x2 + (kk)); \
    float4 v3 = *(const float4*)(x3 + (kk)); \
    acc[(r0)+0] = fmaf(v0.x, GW2(P0,P1,kk), acc[(r0)+0]); acc[(r0)+0] = fmaf(v0.y, GW2(P0,P1,(kk)+1), acc[(r0)+0]); \
    acc[(r0)+0] = fmaf(v0.z, GW2(P0,P1,(kk)+2), acc[(r0)+0]); acc[(r0)+0] = fmaf(v0.w, GW2(P0,P1,(kk)+3), acc[(r0)+0]); \
    acc[(r0)+1] = fmaf(v1.x, GW2(P0,P1,kk), acc[(r0)+1]); acc[(r0)+1] = fmaf(v1.y, GW2(P0,P1,(kk)+1), acc[(r0)+1]); \
    acc[(r0)+1] = fmaf(v1.z, GW2(P0,P1,(kk)+2), acc[(r0)+1]); acc[(r0)+1] = fmaf(v1.w, GW2(P0,P1,(kk)+3), acc[(r0)+1]); \
    acc[(r0)+2] = fmaf(v2.x, GW2(P0,P1,kk), acc[(r0)+2]); acc[(r0)+2] = fmaf(v2.y, GW2(P0,P1,(kk)+1), acc[(r0)+2]); \
    acc[(r0)+2] = fmaf(v2.z, GW2(P0,P1,(kk)+2), acc[(r0)+2]); acc[(r0)+2] = fmaf(v2.w, GW2(P0,P1,(kk)+3), acc[(r0)+2]); \
    acc[(r0)+3] = fmaf(v3.x, GW2(P0,P1,kk), acc[(r0)+3]); acc[(r0)+3] = fmaf(v3.y, GW2(P0,P1,(kk)+1), acc[(r0)+3]); \
    acc[(r0)+3] = fmaf(v3.z, GW2(P0,P1,(kk)+2), acc[(r0)+3]); acc[(r0)+3] = fmaf(v3.w, GW2(P0,P1,(kk)+3), acc[(r0)+3]); }

#define GROW4P(P0,P1,r0,kb) { \
    const float* __restrict__ x0 = xb + (long)((r0)+0) * sT + (kb); \
    const float* __restrict__ x1 = xb + (long)((r0)+1) * sT + (kb); \
    const float* __restrict__ x2 = xb + (long)((r0)+2) * sT + (kb); \
    const float* __restrict__ x3 = xb + (long)((r0)+3) * sT + (kb); \
    GMAC4P(P0,P1,0,r0) GMAC4P(P0,P1,4,r0) GMAC4P(P0,P1,8,r0) GMAC4P(P0,P1,12,r0) \
    GMAC4P(P0,P1,16,r0) GMAC4P(P0,P1,20,r0) GMAC4P(P0,P1,24,r0) GMAC4P(P0,P1,28,r0) }

#define GCOMPP(P0,P1,kb) { \
    GROW4P(P0,P1,0,kb) GROW4P(P0,P1,4,kb) GROW4P(P0,P1,8,kb) GROW4P(P0,P1,12,kb) }

template<int K>
__global__ __launch_bounds__(512) __attribute__((amdgpu_waves_per_eu(4)))
void gemm_gx(const float* __restrict__ X, long sB, int toff,
             const float* __restrict__ WT, const float* __restrict__ bsum,
             float* __restrict__ gx, int Tc)
{
    const int j    = threadIdx.x;
    const int m0   = blockIdx.x * 16;
    const int b    = m0 / Tc;
    const int tcl0 = m0 % Tc;

    constexpr long sT = K;   // compile-time row stride (layer0: FIN, layer1: H)

    const float bj = bsum[j];
    vf16 acc;
#pragma unroll
    for (int r = 0; r < 16; ++r) acc[r] = bj;

    const float* __restrict__ xb = X + (long)b * sB + (long)(toff + tcl0) * sT;
    float* __restrict__ gb = gx + (long)tcl0 * (B * G4) + (long)b * G4 + j;
    const long gstride = (long)B * G4;

    vf16 uA0, uA1, uB0, uB1;

    GLOADP(uA0, uA1, 0)          // chunk 0 weights
    GLOADP(uB0, uB1, 32)         // prefetch chunk 1
    GCOMPP(uA0, uA1, 0)          // compute chunk 0 (hides chunk-1 loads)
    if constexpr (K == 128) {
        GLOADP(uA0, uA1, 64)     // prefetch chunk 2
        GCOMPP(uB0, uB1, 32)
        GLOADP(uB0, uB1, 96)     // prefetch chunk 3
        GCOMPP(uA0, uA1, 64)
        GCOMPP(uB0, uB1, 96)
    } else {
        GCOMPP(uB0, uB1, 32)
    }

#pragma unroll
    for (int r = 0; r < 16; ++r) gb[(long)r * gstride] = acc[r];
}

// ----------------------------------------------------------------------------
// LSTM scan (unchanged from R15/R18 — 210us, VALU-issue-bound at the
// DPP-fmac floor): row_newbcast DPP broadcast fused into the fmac, 2
// ds_read_b128 per wave per step, quad-gate epilogue, 1 barrier/step.
// ----------------------------------------------------------------------------
#define LW8(a,b,c,d,e,f,g,h) float W##a=wp[a],W##b=wp[b],W##c=wp[c],W##d=wp[d], \
                                   W##e=wp[e],W##f=wp[f],W##g=wp[g],W##h=wp[h];
#define TL8(a,b,c,d,e,f,g,h) [W##a]"+v"(W##a),[W##b]"+v"(W##b),[W##c]"+v"(W##c),[W##d]"+v"(W##d), \
                             [W##e]"+v"(W##e),[W##f]"+v"(W##f),[W##g]"+v"(W##g),[W##h]"+v"(W##h)

// 8 fmacs for k = 8N..8N+7: h reg j = k&7, broadcast source lane N = k>>3,
// acc rotation j&3 == k&3 (8N = 0 mod 4). DPP on src0 only; src1 = weight.
#define FMD8(N, w0,w1,w2,w3,w4,w5,w6,w7) \
  "v_fmac_f32 %[a0], %[h0], %[W" #w0 "] row_newbcast:" #N " row_mask:0xf bank_mask:0xf\n\t" \
  "v_fmac_f32 %[a1], %[h1], %[W" #w1 "] row_newbcast:" #N " row_mask:0xf bank_mask:0xf\n\t" \
  "v_fmac_f32 %[a2], %[h2], %[W" #w2 "] row_newbcast:" #N " row_mask:0xf bank_mask:0xf\n\t" \
  "v_fmac_f32 %[a3], %[h3], %[W" #w3 "] row_newbcast:" #N " row_mask:0xf bank_mask:0xf\n\t" \
  "v_fmac_f32 %[a0], %[h4], %[W" #w4 "] row_newbcast:" #N " row_mask:0xf bank_mask:0xf\n\t" \
  "v_fmac_f32 %[a1], %[h5], %[W" #w5 "] row_newbcast:" #N " row_mask:0xf bank_mask:0xf\n\t" \
  "v_fmac_f32 %[a2], %[h6], %[W" #w6 "] row_newbcast:" #N " row_mask:0xf bank_mask:0xf\n\t" \
  "v_fmac_f32 %[a3], %[h7], %[W" #w7 "] row_newbcast:" #N " row_mask:0xf bank_mask:0xf\n\t"

#define HIN [h0]"v"(hA.x),[h1]"v"(hA.y),[h2]"v"(hA.z),[h3]"v"(hA.w), \
            [h4]"v"(hB.x),[h5]"v"(hB.y),[h6]"v"(hB.z),[h7]"v"(hB.w)

#define ACCQ [a0]"+v"(g0),[a1]"+v"(g1),[a2]"+v"(g2),[a3]"+v"(g3)

// padded h layout: h[8r + j] lives at pad[r*12 + j]  (48B row stride,
// 16B-aligned, 2-way bank aliasing across the 16 rows -> conflict-free)
#define HPIDX(k) (((k) >> 3) * 12 + ((k) & 7))
#define HPAD_N   192   // 16 * 12 floats

__global__ __launch_bounds__(512) __attribute__((amdgpu_waves_per_eu(2, 2)))
void lstm_scan(const float* __restrict__ gx, const float* __restrict__ Whh,
               float* __restrict__ h_state, float* __restrict__ c_state,
               float* __restrict__ h1c,     /* null for layer 1 */
               float* __restrict__ h2last,  /* null for layer 0 */
               int Tc, int storeLast)
{
    __shared__ __align__(16) float h_pad[2][HPAD_N];

    const int tid  = threadIdx.x;
    const int b    = blockIdx.x;
    const int gate = tid & 3;        // 0:i 1:f 2:g 3:o
    const int j    = tid >> 2;       // column 0..127
    const int row  = gate * H + j;   // gate row 0..511
    const int lane = tid & 63;
    const int r16  = lane & 15;      // 16-lane row index

    const float* __restrict__ wp = Whh + (long)row * H;
    LW8(0,1,2,3,4,5,6,7)           LW8(8,9,10,11,12,13,14,15)
    LW8(16,17,18,19,20,21,22,23)   LW8(24,25,26,27,28,29,30,31)
    LW8(32,33,34,35,36,37,38,39)   LW8(40,41,42,43,44,45,46,47)
    LW8(48,49,50,51,52,53,54,55)   LW8(56,57,58,59,60,61,62,63)
    LW8(64,65,66,67,68,69,70,71)   LW8(72,73,74,75,76,77,78,79)
    LW8(80,81,82,83,84,85,86,87)   LW8(88,89,90,91,92,93,94,95)
    LW8(96,97,98,99,100,101,102,103)    LW8(104,105,106,107,108,109,110,111)
    LW8(112,113,114,115,116,117,118,119) LW8(120,121,122,123,124,125,126,127)
    // Opaque touches: weights become asm-defined values (remat illegal).
    asm("" : TL8(0,1,2,3,4,5,6,7), TL8(8,9,10,11,12,13,14,15),
             TL8(16,17,18,19,20,21,22,23), TL8(24,25,26,27,28,29,30,31));
    asm("" : TL8(32,33,34,35,36,37,38,39), TL8(40,41,42,43,44,45,46,47),
             TL8(48,49,50,51,52,53,54,55), TL8(56,57,58,59,60,61,62,63));
    asm("" : TL8(64,65,66,67,68,69,70,71), TL8(72,73,74,75,76,77,78,79),
             TL8(80,81,82,83,84,85,86,87), TL8(88,89,90,91,92,93,94,95));
    asm("" : TL8(96,97,98,99,100,101,102,103), TL8(104,105,106,107,108,109,110,111),
             TL8(112,113,114,115,116,117,118,119), TL8(120,121,122,123,124,125,126,127));

    const bool istanh = (gate == 2);
    const float kk = istanh ? (-2.f * LOG2E) : (-LOG2E);
    const float aa = istanh ? 2.f : 1.f;
    const float bb = istanh ? -1.f : 0.f;

    float c = 0.f;
    if (tid < H) h_pad[0][HPIDX(tid)] = h_state[b * H + tid];
    if (gate == 0) c = c_state[b * H + j];
    __syncthreads();

    const long gstride = (long)B * G4;
    const float* __restrict__ gxp = gx + (long)b * G4 + row;
    float gc = gxp[0];
    float gn = (Tc > 1) ? gxp[gstride] : 0.f;

    int cur = 0;

    for (int t = 0; t < Tc; ++t) {
        float gn2 = (t + 2 < Tc) ? gxp[(long)(t + 2) * gstride] : 0.f;

        const float* __restrict__ hp = &h_pad[cur][0] + r16 * 12;
        float4 hA = *(const float4*)(hp);
        float4 hB = *(const float4*)(hp + 4);

        float g0 = gc, g1 = 0.f, g2 = 0.f, g3 = 0.f;

        asm("s_nop 1\n\t"
            FMD8(0, 0,1,2,3,4,5,6,7)
            FMD8(1, 8,9,10,11,12,13,14,15)
            FMD8(2, 16,17,18,19,20,21,22,23)
            FMD8(3, 24,25,26,27,28,29,30,31)
            : ACCQ, TL8(0,1,2,3,4,5,6,7), TL8(8,9,10,11,12,13,14,15),
              TL8(16,17,18,19,20,21,22,23), TL8(24,25,26,27,28,29,30,31)
            : HIN);

        asm("s_nop 1\n\t"
            FMD8(4, 32,33,34,35,36,37,38,39)
            FMD8(5, 40,41,42,43,44,45,46,47)
            FMD8(6, 48,49,50,51,52,53,54,55)
            FMD8(7, 56,57,58,59,60,61,62,63)
            : ACCQ, TL8(32,33,34,35,36,37,38,39), TL8(40,41,42,43,44,45,46,47),
              TL8(48,49,50,51,52,53,54,55), TL8(56,57,58,59,60,61,62,63)
            : HIN);

        asm("s_nop 1\n\t"
            FMD8(8,  64,65,66,67,68,69,70,71)
            FMD8(9,  72,73,74,75,76,77,78,79)
            FMD8(10, 80,81,82,83,84,85,86,87)
            FMD8(11, 88,89,90,91,92,93,94,95)
            : ACCQ, TL8(64,65,66,67,68,69,70,71), TL8(72,73,74,75,76,77,78,79),
              TL8(80,81,82,83,84,85,86,87), TL8(88,89,90,91,92,93,94,95)
            : HIN);

        asm("s_nop 1\n\t"
            FMD8(12, 96,97,98,99,100,101,102,103)
            FMD8(13, 104,105,106,107,108,109,110,111)
            FMD8(14, 112,113,114,115,116,117,118,119)
            FMD8(15, 120,121,122,123,124,125,126,127)
            : ACCQ, TL8(96,97,98,99,100,101,102,103), TL8(104,105,106,107,108,109,110,111),
              TL8(112,113,114,115,116,117,118,119), TL8(120,121,122,123,124,125,126,127)
            : HIN);

        float g = (g0 + g1) + (g2 + g3);

        float e = __builtin_amdgcn_exp2f(kk * g);
        float s = __builtin_amdgcn_rcpf(1.f + e);
        float v = fmaf(aa, s, bb);   // own gate value

        // in-quad gather: v^1, v^2, v^3 via DPP quad_perm (all lanes active)
        float x1 = QXOR1(v);
        float x2 = QXOR2(v);
        float x3 = QXOR1(x2);

        if (gate == 0) {
            // for gate-0 lane: i = v, f = x1, g = x2, o = x3
            c = fmaf(x1, c, v * x2);
            float hn = x3 * fast_tanh(c);
            h_pad[cur ^ 1][HPIDX(j)] = hn;
            if (h1c) h1c[(long)b * Tc * H + (long)t * H + j] = hn;
            if (storeLast && t == Tc - 1) h2last[b * H + j] = hn;
        }
        __syncthreads();
        cur ^= 1;
        gc = gn; gn = gn2;
    }

    if (tid < H) h_state[b * H + tid] = h_pad[cur][HPIDX(tid)];
    if (gate == 0) c_state[b * H + j] = c;
}

// ----------------------------------------------------------------------------
// Dropout: JAX threefry2x32, jax_threefry_partitionable=True (default since
// jax 0.4.36): counter (0, e), bits = y0 ^ y1, key (0, 42).
// ----------------------------------------------------------------------------
__device__ __forceinline__ uint32_t rotl32(uint32_t x, int r) { return (x << r) | (x >> (32 - r)); }

__global__ void dropout_kernel(const float* __restrict__ h2last, float* __restrict__ h2drop)
{
    int e = blockIdx.x * blockDim.x + threadIdx.x;
    if (e >= B * H) return;
    const uint32_t k0 = 0u, k1 = 42u, k2 = 0u ^ 42u ^ 0x1BD11BDAu;
    uint32_t x0 = 0u;
    uint32_t x1 = (uint32_t)e;
    x0 += k0; x1 += k1;
#define RG(ra,rb,rc,rd,ka,kb,inc) \
    x0 += x1; x1 = rotl32(x1, ra); x1 ^= x0; \
    x0 += x1; x1 = rotl32(x1, rb); x1 ^= x0; \
    x0 += x1; x1 = rotl32(x1, rc); x1 ^= x0; \
    x0 += x1; x1 = rotl32(x1, rd); x1 ^= x0; \
    x0 += ka; x1 += kb + inc;
    RG(13,15,26, 6, k1, k2, 1u)
    RG(17,29,16,24, k2, k0, 2u)
    RG(13,15,26, 6, k0, k1, 3u)
    RG(17,29,16,24, k1, k2, 4u)
    RG(13,15,26, 6, k2, k0, 5u)
#undef RG
    uint32_t bits = x0 ^ x1;
    float u = __uint_as_float((bits >> 9) | 0x3f800000u) - 1.0f;
    float a = h2last[e];
    h2drop[e] = (u >= 0.3f) ? (a / 0.7f) : 0.0f;
}

// ----------------------------------------------------------------------------
// Head: out[b][n] = b_out[n] + sum_u h2drop[b][u] * W_out[n][u]
// ----------------------------------------------------------------------------
__global__ void out_kernel(const float* __restrict__ h2drop, const float* __restrict__ W_out,
                           const float* __restrict__ b_out, float* __restrict__ out)
{
    int i = blockIdx.x * blockDim.x + threadIdx.x;
    if (i >= B * 2) return;
    int bb = i >> 1, n = i & 1;
    float acc = b_out[n];
    const float* __restrict__ hp = h2drop + (long)bb * H;
    const float* __restrict__ wp = W_out + (long)n * H;
#pragma unroll 4
    for (int u = 0; u < H; ++u) acc = fmaf(hp[u], wp[u], acc);
    out[i] = acc;
}

// ----------------------------------------------------------------------------
extern "C" void kernel_launch(void* const* d_in, const int* in_sizes, int n_in,
                              void* d_out, int out_size, void* d_ws, size_t ws_size,
                              hipStream_t stream)
{
    const float* x     = (const float*)d_in[0];
    const float* W_ih0 = (const float*)d_in[1];
    const float* W_hh0 = (const float*)d_in[2];
    const float* b_ih0 = (const float*)d_in[3];
    const float* b_hh0 = (const float*)d_in[4];
    const float* W_ih1 = (const float*)d_in[5];
    const float* W_hh1 = (const float*)d_in[6];
    const float* b_ih1 = (const float*)d_in[7];
    const float* b_hh1 = (const float*)d_in[8];
    const float* W_out = (const float*)d_in[9];
    const float* b_out = (const float*)d_in[10];
    float* out = (float*)d_out;

    char* ws = (char*)d_ws;
    size_t off = 0;
    auto alloc = [&](size_t bytes) { void* p = ws + off; off += (bytes + 255) & ~255ull; return p; };

    float* WT0    = (float*)alloc((size_t)FIN * G4 * 4);
    float* WT1    = (float*)alloc((size_t)H * G4 * 4);
    float* bsum0  = (float*)alloc((size_t)G4 * 4);
    float* bsum1  = (float*)alloc((size_t)G4 * 4);
    float* states = (float*)alloc((size_t)4 * B * H * 4);
    float* h0s = states, *c0s = states + B * H, *h1s = states + 2 * B * H, *c1s = states + 3 * B * H;
    float* h2last = (float*)alloc((size_t)B * H * 4);
    float* h2drop = (float*)alloc((size_t)B * H * 4);

    size_t fixed = off;
    int Tc = 16;
    const int cands[7] = {1024, 512, 256, 128, 64, 32, 16};
    for (int ci = 0; ci < 7; ++ci) {
        size_t need = fixed + (size_t)cands[ci] * ((size_t)B * H * 4 + (size_t)B * G4 * 4) + 8192;
        if (need <= ws_size) { Tc = cands[ci]; break; }
    }
    float* h1c = (float*)alloc((size_t)B * Tc * H * 4);
    float* gxb = (float*)alloc((size_t)Tc * B * G4 * 4);

    fprintf(stderr, "[kernel_launch] ws_size=%zu fixed=%zu Tc=%d total_used=%zu\n",
            ws_size, fixed, Tc, off);

    prep_kernel<<<512, 256, 0, stream>>>(W_ih0, b_ih0, b_hh0, W_ih1, b_ih1, b_hh1,
                                         WT0, WT1, bsum0, bsum1, states);

    const int nch = T / Tc;
    for (int c = 0; c < nch; ++c) {
        int t0 = c * Tc;
        gemm_gx<FIN><<<(B * Tc) / 16, 512, 0, stream>>>(x, (long)T * FIN, t0,
                                                        WT0, bsum0, gxb, Tc);
        lstm_scan<<<B, 512, 0, stream>>>(gxb, W_hh0, h0s, c0s, h1c, nullptr, Tc, 0);
        gemm_gx<H><<<(B * Tc) / 16, 512, 0, stream>>>(h1c, (long)Tc * H, 0,
                                                      WT1, bsum1, gxb, Tc);
        lstm_scan<<<B, 512, 0, stream>>>(gxb, W_hh1, h1s, c1s, nullptr, h2last, Tc,
                                         (t0 + Tc == T) ? 1 : 0);
    }

    dropout_kernel<<<128, 256, 0, stream>>>(h2last, h2drop);
    out_kernel<<<2, 256, 0, stream>>>(h2drop, W_out, b_out, out);
}

// Round 14
// 2476.952 us; speedup vs baseline: 1.0768x; 1.0768x over previous
//
#include <hip/hip_runtime.h>
#include <stdint.h>
#include <cstdio>

#define B   256
#define T   1024
#define FIN 64
#define H   128
#define G4  512   // 4*H

typedef float vf16 __attribute__((ext_vector_type(16)));

// Inline activations (no OCML calls — R8: calls forced spills around them).
#define LOG2E 1.442695041f
__device__ __forceinline__ float fast_tanh(float x) {
    return fmaf(2.f, __builtin_amdgcn_rcpf(1.f + __builtin_amdgcn_exp2f(-2.f * LOG2E * x)), -1.f);
}

// DPP quad_perm cross-lane (VALU pipe, no LDS): xor1 = [1,0,3,2] = 0xB1,
// xor2 = [2,3,0,1] = 0x4E. lane^3 = QXOR1(QXOR2(x)).
#define QXOR1(x) __int_as_float(__builtin_amdgcn_update_dpp(0, __float_as_int(x), 0xB1, 0xf, 0xf, true))
#define QXOR2(x) __int_as_float(__builtin_amdgcn_update_dpp(0, __float_as_int(x), 0x4E, 0xf, 0xf, true))

// ----------------------------------------------------------------------------
// prep: W_ih -> PACKED WTP[k/4][j][4] (4 consecutive-k weights of column j
// contiguous -> gemm loads them as ONE coalesced float4), bias sums, zero
// recurrent states.
// ----------------------------------------------------------------------------
__global__ void prep_kernel(const float* __restrict__ W_ih0,
                            const float* __restrict__ b_ih0, const float* __restrict__ b_hh0,
                            const float* __restrict__ W_ih1,
                            const float* __restrict__ b_ih1, const float* __restrict__ b_hh1,
                            float* __restrict__ WT0, float* __restrict__ WT1,
                            float* __restrict__ bsum0, float* __restrict__ bsum1,
                            float* __restrict__ states /* 4*B*H */)
{
    int idx = blockIdx.x * blockDim.x + threadIdx.x;
    int n   = gridDim.x * blockDim.x;
    for (int i = idx; i < H * G4; i += n) {
        int k = i / G4, j = i % G4;
        WT1[(long)(k >> 2) * (G4 * 4) + j * 4 + (k & 3)] = W_ih1[j * H + k];
    }
    for (int i = idx; i < FIN * G4; i += n) {
        int k = i / G4, j = i % G4;
        WT0[(long)(k >> 2) * (G4 * 4) + j * 4 + (k & 3)] = W_ih0[j * FIN + k];
    }
    for (int i = idx; i < G4; i += n) { bsum0[i] = b_ih0[i] + b_hh0[i]; bsum1[i] = b_ih1[i] + b_hh1[i]; }
    for (int i = idx; i < 4 * B * H; i += n) states[i] = 0.f;
}

// ----------------------------------------------------------------------------
// gx GEMM, R22: R18/R20 structure (ROWS=16, single vf16 acc, constexpr
// stride, waves_per_eu(4) — the 2544us best) + PACKED weight loads:
// 128 strided dword weight-loads -> 32 coalesced float4 loads per thread.
//
// R21 post-mortem: explicit dbuf regressed (+64 regs). No room for more
// register state; attack the VMEM instruction count instead. Weight values
// and per-output fmac order identical -> bitwise-identical gx.
// ----------------------------------------------------------------------------
#define GW(n)    ((n) < 16 ? u0[(n) & 15] : u1[(n) & 15])
#define GWS(n,v) do { if ((n) < 16) u0[(n) & 15] = (v); else u1[(n) & 15] = (v); } while (0)

// one float4 = weights k=kb+n..kb+n+3 of column j (packed layout)
#define GLD4(n) { float4 w = *(const float4*)(wp0 + (long)((n) >> 2) * (G4 * 4)); \
    GWS((n), w.x); GWS((n)+1, w.y); GWS((n)+2, w.z); GWS((n)+3, w.w); }

#define GMAC4(kk, r0) { \
    float4 v0 = *(const float4*)(x0 + (kk)); \
    float4 v1 = *(const float4*)(x1 + (kk)); \
    float4 v2 = *(const float4*)(x2 + (kk)); \
    float4 v3 = *(const float4*)(x3 + (kk)); \
    acc[(r0)+0] = fmaf(v0.x, GW(kk), acc[(r0)+0]); acc[(r0)+0] = fmaf(v0.y, GW((kk)+1), acc[(r0)+0]); \
    acc[(r0)+0] = fmaf(v0.z, GW((kk)+2), acc[(r0)+0]); acc[(r0)+0] = fmaf(v0.w, GW((kk)+3), acc[(r0)+0]); \
    acc[(r0)+1] = fmaf(v1.x, GW(kk), acc[(r0)+1]); acc[(r0)+1] = fmaf(v1.y, GW((kk)+1), acc[(r0)+1]); \
    acc[(r0)+1] = fmaf(v1.z, GW((kk)+2), acc[(r0)+1]); acc[(r0)+1] = fmaf(v1.w, GW((kk)+3), acc[(r0)+1]); \
    acc[(r0)+2] = fmaf(v2.x, GW(kk), acc[(r0)+2]); acc[(r0)+2] = fmaf(v2.y, GW((kk)+1), acc[(r0)+2]); \
    acc[(r0)+2] = fmaf(v2.z, GW((kk)+2), acc[(r0)+2]); acc[(r0)+2] = fmaf(v2.w, GW((kk)+3), acc[(r0)+2]); \
    acc[(r0)+3] = fmaf(v3.x, GW(kk), acc[(r0)+3]); acc[(r0)+3] = fmaf(v3.y, GW((kk)+1), acc[(r0)+3]); \
    acc[(r0)+3] = fmaf(v3.z, GW((kk)+2), acc[(r0)+3]); acc[(r0)+3] = fmaf(v3.w, GW((kk)+3), acc[(r0)+3]); }

#define GROW4(r0, kb) { \
    const float* __restrict__ x0 = xb + (long)((r0)+0) * sT + (kb); \
    const float* __restrict__ x1 = xb + (long)((r0)+1) * sT + (kb); \
    const float* __restrict__ x2 = xb + (long)((r0)+2) * sT + (kb); \
    const float* __restrict__ x3 = xb + (long)((r0)+3) * sT + (kb); \
    GMAC4(0,r0) GMAC4(4,r0) GMAC4(8,r0) GMAC4(12,r0) \
    GMAC4(16,r0) GMAC4(20,r0) GMAC4(24,r0) GMAC4(28,r0) }

#define GCHUNK(kb) { \
    vf16 u0, u1; \
    const float* __restrict__ wp0 = WT + (long)((kb) >> 2) * (G4 * 4) + j * 4; \
    GLD4(0) GLD4(4) GLD4(8) GLD4(12) GLD4(16) GLD4(20) GLD4(24) GLD4(28) \
    GROW4(0,kb) GROW4(4,kb) GROW4(8,kb) GROW4(12,kb) }

template<int K>
__global__ __launch_bounds__(512) __attribute__((amdgpu_waves_per_eu(4)))
void gemm_gx(const float* __restrict__ X, long sB, int toff,
             const float* __restrict__ WT, const float* __restrict__ bsum,
             float* __restrict__ gx, int Tc)
{
    const int j    = threadIdx.x;
    const int m0   = blockIdx.x * 16;
    const int b    = m0 / Tc;
    const int tcl0 = m0 % Tc;

    constexpr long sT = K;   // compile-time row stride (layer0: FIN, layer1: H)

    const float bj = bsum[j];
    vf16 acc;
#pragma unroll
    for (int r = 0; r < 16; ++r) acc[r] = bj;

    const float* __restrict__ xb = X + (long)b * sB + (long)(toff + tcl0) * sT;
    float* __restrict__ gb = gx + (long)tcl0 * (B * G4) + (long)b * G4 + j;
    const long gstride = (long)B * G4;

    GCHUNK(0) GCHUNK(32)
    if constexpr (K == 128) { GCHUNK(64) GCHUNK(96) }

#pragma unroll
    for (int r = 0; r < 16; ++r) gb[(long)r * gstride] = acc[r];
}

// ----------------------------------------------------------------------------
// LSTM scan (unchanged from R15/R18 — 210us, VALU-issue-bound at the
// DPP-fmac floor): row_newbcast DPP broadcast fused into the fmac, 2
// ds_read_b128 per wave per step, quad-gate epilogue, 1 barrier/step.
// ----------------------------------------------------------------------------
#define LW8(a,b,c,d,e,f,g,h) float W##a=wp[a],W##b=wp[b],W##c=wp[c],W##d=wp[d], \
                                   W##e=wp[e],W##f=wp[f],W##g=wp[g],W##h=wp[h];
#define TL8(a,b,c,d,e,f,g,h) [W##a]"+v"(W##a),[W##b]"+v"(W##b),[W##c]"+v"(W##c),[W##d]"+v"(W##d), \
                             [W##e]"+v"(W##e),[W##f]"+v"(W##f),[W##g]"+v"(W##g),[W##h]"+v"(W##h)

// 8 fmacs for k = 8N..8N+7: h reg j = k&7, broadcast source lane N = k>>3,
// acc rotation j&3 == k&3 (8N = 0 mod 4). DPP on src0 only; src1 = weight.
#define FMD8(N, w0,w1,w2,w3,w4,w5,w6,w7) \
  "v_fmac_f32 %[a0], %[h0], %[W" #w0 "] row_newbcast:" #N " row_mask:0xf bank_mask:0xf\n\t" \
  "v_fmac_f32 %[a1], %[h1], %[W" #w1 "] row_newbcast:" #N " row_mask:0xf bank_mask:0xf\n\t" \
  "v_fmac_f32 %[a2], %[h2], %[W" #w2 "] row_newbcast:" #N " row_mask:0xf bank_mask:0xf\n\t" \
  "v_fmac_f32 %[a3], %[h3], %[W" #w3 "] row_newbcast:" #N " row_mask:0xf bank_mask:0xf\n\t" \
  "v_fmac_f32 %[a0], %[h4], %[W" #w4 "] row_newbcast:" #N " row_mask:0xf bank_mask:0xf\n\t" \
  "v_fmac_f32 %[a1], %[h5], %[W" #w5 "] row_newbcast:" #N " row_mask:0xf bank_mask:0xf\n\t" \
  "v_fmac_f32 %[a2], %[h6], %[W" #w6 "] row_newbcast:" #N " row_mask:0xf bank_mask:0xf\n\t" \
  "v_fmac_f32 %[a3], %[h7], %[W" #w7 "] row_newbcast:" #N " row_mask:0xf bank_mask:0xf\n\t"

#define HIN [h0]"v"(hA.x),[h1]"v"(hA.y),[h2]"v"(hA.z),[h3]"v"(hA.w), \
            [h4]"v"(hB.x),[h5]"v"(hB.y),[h6]"v"(hB.z),[h7]"v"(hB.w)

#define ACCQ [a0]"+v"(g0),[a1]"+v"(g1),[a2]"+v"(g2),[a3]"+v"(g3)

// padded h layout: h[8r + j] lives at pad[r*12 + j]  (48B row stride,
// 16B-aligned, 2-way bank aliasing across the 16 rows -> conflict-free)
#define HPIDX(k) (((k) >> 3) * 12 + ((k) & 7))
#define HPAD_N   192   // 16 * 12 floats

__global__ __launch_bounds__(512) __attribute__((amdgpu_waves_per_eu(2, 2)))
void lstm_scan(const float* __restrict__ gx, const float* __restrict__ Whh,
               float* __restrict__ h_state, float* __restrict__ c_state,
               float* __restrict__ h1c,     /* null for layer 1 */
               float* __restrict__ h2last,  /* null for layer 0 */
               int Tc, int storeLast)
{
    __shared__ __align__(16) float h_pad[2][HPAD_N];

    const int tid  = threadIdx.x;
    const int b    = blockIdx.x;
    const int gate = tid & 3;        // 0:i 1:f 2:g 3:o
    const int j    = tid >> 2;       // column 0..127
    const int row  = gate * H + j;   // gate row 0..511
    const int lane = tid & 63;
    const int r16  = lane & 15;      // 16-lane row index

    const float* __restrict__ wp = Whh + (long)row * H;
    LW8(0,1,2,3,4,5,6,7)           LW8(8,9,10,11,12,13,14,15)
    LW8(16,17,18,19,20,21,22,23)   LW8(24,25,26,27,28,29,30,31)
    LW8(32,33,34,35,36,37,38,39)   LW8(40,41,42,43,44,45,46,47)
    LW8(48,49,50,51,52,53,54,55)   LW8(56,57,58,59,60,61,62,63)
    LW8(64,65,66,67,68,69,70,71)   LW8(72,73,74,75,76,77,78,79)
    LW8(80,81,82,83,84,85,86,87)   LW8(88,89,90,91,92,93,94,95)
    LW8(96,97,98,99,100,101,102,103)    LW8(104,105,106,107,108,109,110,111)
    LW8(112,113,114,115,116,117,118,119) LW8(120,121,122,123,124,125,126,127)
    // Opaque touches: weights become asm-defined values (remat illegal).
    asm("" : TL8(0,1,2,3,4,5,6,7), TL8(8,9,10,11,12,13,14,15),
             TL8(16,17,18,19,20,21,22,23), TL8(24,25,26,27,28,29,30,31));
    asm("" : TL8(32,33,34,35,36,37,38,39), TL8(40,41,42,43,44,45,46,47),
             TL8(48,49,50,51,52,53,54,55), TL8(56,57,58,59,60,61,62,63));
    asm("" : TL8(64,65,66,67,68,69,70,71), TL8(72,73,74,75,76,77,78,79),
             TL8(80,81,82,83,84,85,86,87), TL8(88,89,90,91,92,93,94,95));
    asm("" : TL8(96,97,98,99,100,101,102,103), TL8(104,105,106,107,108,109,110,111),
             TL8(112,113,114,115,116,117,118,119), TL8(120,121,122,123,124,125,126,127));

    const bool istanh = (gate == 2);
    const float kk = istanh ? (-2.f * LOG2E) : (-LOG2E);
    const float aa = istanh ? 2.f : 1.f;
    const float bb = istanh ? -1.f : 0.f;

    float c = 0.f;
    if (tid < H) h_pad[0][HPIDX(tid)] = h_state[b * H + tid];
    if (gate == 0) c = c_state[b * H + j];
    __syncthreads();

    const long gstride = (long)B * G4;
    const float* __restrict__ gxp = gx + (long)b * G4 + row;
    float gc = gxp[0];
    float gn = (Tc > 1) ? gxp[gstride] : 0.f;

    int cur = 0;

    for (int t = 0; t < Tc; ++t) {
        float gn2 = (t + 2 < Tc) ? gxp[(long)(t + 2) * gstride] : 0.f;

        const float* __restrict__ hp = &h_pad[cur][0] + r16 * 12;
        float4 hA = *(const float4*)(hp);
        float4 hB = *(const float4*)(hp + 4);

        float g0 = gc, g1 = 0.f, g2 = 0.f, g3 = 0.f;

        asm("s_nop 1\n\t"
            FMD8(0, 0,1,2,3,4,5,6,7)
            FMD8(1, 8,9,10,11,12,13,14,15)
            FMD8(2, 16,17,18,19,20,21,22,23)
            FMD8(3, 24,25,26,27,28,29,30,31)
            : ACCQ, TL8(0,1,2,3,4,5,6,7), TL8(8,9,10,11,12,13,14,15),
              TL8(16,17,18,19,20,21,22,23), TL8(24,25,26,27,28,29,30,31)
            : HIN);

        asm("s_nop 1\n\t"
            FMD8(4, 32,33,34,35,36,37,38,39)
            FMD8(5, 40,41,42,43,44,45,46,47)
            FMD8(6, 48,49,50,51,52,53,54,55)
            FMD8(7, 56,57,58,59,60,61,62,63)
            : ACCQ, TL8(32,33,34,35,36,37,38,39), TL8(40,41,42,43,44,45,46,47),
              TL8(48,49,50,51,52,53,54,55), TL8(56,57,58,59,60,61,62,63)
            : HIN);

        asm("s_nop 1\n\t"
            FMD8(8,  64,65,66,67,68,69,70,71)
            FMD8(9,  72,73,74,75,76,77,78,79)
            FMD8(10, 80,81,82,83,84,85,86,87)
            FMD8(11, 88,89,90,91,92,93,94,95)
            : ACCQ, TL8(64,65,66,67,68,69,70,71), TL8(72,73,74,75,76,77,78,79),
              TL8(80,81,82,83,84,85,86,87), TL8(88,89,90,91,92,93,94,95)
            : HIN);

        asm("s_nop 1\n\t"
            FMD8(12, 96,97,98,99,100,101,102,103)
            FMD8(13, 104,105,106,107,108,109,110,111)
            FMD8(14, 112,113,114,115,116,117,118,119)
            FMD8(15, 120,121,122,123,124,125,126,127)
            : ACCQ, TL8(96,97,98,99,100,101,102,103), TL8(104,105,106,107,108,109,110,111),
              TL8(112,113,114,115,116,117,118,119), TL8(120,121,122,123,124,125,126,127)
            : HIN);

        float g = (g0 + g1) + (g2 + g3);

        float e = __builtin_amdgcn_exp2f(kk * g);
        float s = __builtin_amdgcn_rcpf(1.f + e);
        float v = fmaf(aa, s, bb);   // own gate value

        // in-quad gather: v^1, v^2, v^3 via DPP quad_perm (all lanes active)
        float x1 = QXOR1(v);
        float x2 = QXOR2(v);
        float x3 = QXOR1(x2);

        if (gate == 0) {
            // for gate-0 lane: i = v, f = x1, g = x2, o = x3
            c = fmaf(x1, c, v * x2);
            float hn = x3 * fast_tanh(c);
            h_pad[cur ^ 1][HPIDX(j)] = hn;
            if (h1c) h1c[(long)b * Tc * H + (long)t * H + j] = hn;
            if (storeLast && t == Tc - 1) h2last[b * H + j] = hn;
        }
        __syncthreads();
        cur ^= 1;
        gc = gn; gn = gn2;
    }

    if (tid < H) h_state[b * H + tid] = h_pad[cur][HPIDX(tid)];
    if (gate == 0) c_state[b * H + j] = c;
}

// ----------------------------------------------------------------------------
// Dropout: JAX threefry2x32, jax_threefry_partitionable=True (default since
// jax 0.4.36): counter (0, e), bits = y0 ^ y1, key (0, 42).
// ----------------------------------------------------------------------------
__device__ __forceinline__ uint32_t rotl32(uint32_t x, int r) { return (x << r) | (x >> (32 - r)); }

__global__ void dropout_kernel(const float* __restrict__ h2last, float* __restrict__ h2drop)
{
    int e = blockIdx.x * blockDim.x + threadIdx.x;
    if (e >= B * H) return;
    const uint32_t k0 = 0u, k1 = 42u, k2 = 0u ^ 42u ^ 0x1BD11BDAu;
    uint32_t x0 = 0u;
    uint32_t x1 = (uint32_t)e;
    x0 += k0; x1 += k1;
#define RG(ra,rb,rc,rd,ka,kb,inc) \
    x0 += x1; x1 = rotl32(x1, ra); x1 ^= x0; \
    x0 += x1; x1 = rotl32(x1, rb); x1 ^= x0; \
    x0 += x1; x1 = rotl32(x1, rc); x1 ^= x0; \
    x0 += x1; x1 = rotl32(x1, rd); x1 ^= x0; \
    x0 += ka; x1 += kb + inc;
    RG(13,15,26, 6, k1, k2, 1u)
    RG(17,29,16,24, k2, k0, 2u)
    RG(13,15,26, 6, k0, k1, 3u)
    RG(17,29,16,24, k1, k2, 4u)
    RG(13,15,26, 6, k2, k0, 5u)
#undef RG
    uint32_t bits = x0 ^ x1;
    float u = __uint_as_float((bits >> 9) | 0x3f800000u) - 1.0f;
    float a = h2last[e];
    h2drop[e] = (u >= 0.3f) ? (a / 0.7f) : 0.0f;
}

// ----------------------------------------------------------------------------
// Head: out[b][n] = b_out[n] + sum_u h2drop[b][u] * W_out[n][u]
// ----------------------------------------------------------------------------
__global__ void out_kernel(const float* __restrict__ h2drop, const float* __restrict__ W_out,
                           const float* __restrict__ b_out, float* __restrict__ out)
{
    int i = blockIdx.x * blockDim.x + threadIdx.x;
    if (i >= B * 2) return;
    int bb = i >> 1, n = i & 1;
    float acc = b_out[n];
    const float* __restrict__ hp = h2drop + (long)bb * H;
    const float* __restrict__ wp = W_out + (long)n * H;
#pragma unroll 4
    for (int u = 0; u < H; ++u) acc = fmaf(hp[u], wp[u], acc);
    out[i] = acc;
}

// ----------------------------------------------------------------------------
extern "C" void kernel_launch(void* const* d_in, const int* in_sizes, int n_in,
                              void* d_out, int out_size, void* d_ws, size_t ws_size,
                              hipStream_t stream)
{
    const float* x     = (const float*)d_in[0];
    const float* W_ih0 = (const float*)d_in[1];
    const float* W_hh0 = (const float*)d_in[2];
    const float* b_ih0 = (const float*)d_in[3];
    const float* b_hh0 = (const float*)d_in[4];
    const float* W_ih1 = (const float*)d_in[5];
    const float* W_hh1 = (const float*)d_in[6];
    const float* b_ih1 = (const float*)d_in[7];
    const float* b_hh1 = (const float*)d_in[8];
    const float* W_out = (const float*)d_in[9];
    const float* b_out = (const float*)d_in[10];
    float* out = (float*)d_out;

    char* ws = (char*)d_ws;
    size_t off = 0;
    auto alloc = [&](size_t bytes) { void* p = ws + off; off += (bytes + 255) & ~255ull; return p; };

    float* WT0    = (float*)alloc((size_t)FIN * G4 * 4);
    float* WT1    = (float*)alloc((size_t)H * G4 * 4);
    float* bsum0  = (float*)alloc((size_t)G4 * 4);
    float* bsum1  = (float*)alloc((size_t)G4 * 4);
    float* states = (float*)alloc((size_t)4 * B * H * 4);
    float* h0s = states, *c0s = states + B * H, *h1s = states + 2 * B * H, *c1s = states + 3 * B * H;
    float* h2last = (float*)alloc((size_t)B * H * 4);
    float* h2drop = (float*)alloc((size_t)B * H * 4);

    size_t fixed = off;
    int Tc = 16;
    const int cands[7] = {1024, 512, 256, 128, 64, 32, 16};
    for (int ci = 0; ci < 7; ++ci) {
        size_t need = fixed + (size_t)cands[ci] * ((size_t)B * H * 4 + (size_t)B * G4 * 4) + 8192;
        if (need <= ws_size) { Tc = cands[ci]; break; }
    }
    float* h1c = (float*)alloc((size_t)B * Tc * H * 4);
    float* gxb = (float*)alloc((size_t)Tc * B * G4 * 4);

    fprintf(stderr, "[kernel_launch] ws_size=%zu fixed=%zu Tc=%d total_used=%zu\n",
            ws_size, fixed, Tc, off);

    prep_kernel<<<512, 256, 0, stream>>>(W_ih0, b_ih0, b_hh0, W_ih1, b_ih1, b_hh1,
                                         WT0, WT1, bsum0, bsum1, states);

    const int nch = T / Tc;
    for (int c = 0; c < nch; ++c) {
        int t0 = c * Tc;
        gemm_gx<FIN><<<(B * Tc) / 16, 512, 0, stream>>>(x, (long)T * FIN, t0,
                                                        WT0, bsum0, gxb, Tc);
        lstm_scan<<<B, 512, 0, stream>>>(gxb, W_hh0, h0s, c0s, h1c, nullptr, Tc, 0);
        gemm_gx<H><<<(B * Tc) / 16, 512, 0, stream>>>(h1c, (long)Tc * H, 0,
                                                      WT1, bsum1, gxb, Tc);
        lstm_scan<<<B, 512, 0, stream>>>(gxb, W_hh1, h1s, c1s, nullptr, h2last, Tc,
                                         (t0 + Tc == T) ? 1 : 0);
    }

    dropout_kernel<<<128, 256, 0, stream>>>(h2last, h2drop);
    out_kernel<<<2, 256, 0, stream>>>(h2drop, W_out, b_out, out);
}